// Round 11
// baseline (265.955 us; speedup 1.0000x reference)
//
#include <hip/hip_runtime.h>
#include <hip/hip_bf16.h>
#include <hip/hip_fp16.h>
#include <cstddef>

// ---------------------------------------------------------------------------
// GCN: 3x GraphConv(norm='both') + relu + threefry dropout (p=0.5)
//   Aggregate-first identity: ndst (A (nsrc.h) W) == ndst (A (nsrc.h)) W.
//   Gather buffers G are FP16 row-major; all accumulation stays FP32.
//
//   r11 = r10 + fine buckets (NB_W 512->256) to kill preprocessing's LDS-
//   atomic serialization: r10 preproc ~100us for ~40MB of traffic (~20us
//   worth). bin_k had 1024 lanes on 256 LDS counters = 4-way collisions
//   (m136: 1.58x, worse with returns); role_k ran 392 blocks = 1.5/CU.
//   Now: 391 buckets of 256 nodes; bin_k EB=2048/WGB=512 with 512-entry
//   hists = ~1 lane/counter (conflict-free regime) + int4 edge loads;
//   role_k 782 blocks x 512. srcloc fits u8 -> binbufS 2.2MB.
//   - bin_k: dual LDS counting-sort (dst+src bucket) -> dense per-
//     (bucket,xcdgrp) sub-runs via split global cursors (curs[x][b], only
//     blocks with bid&7==x touch row x).
//   - role_k: dst role = dense sub-run read x2 (count -> 4-padded scan ->
//     exact bucket-local CSR scatter), meta[v]=(off<<8)|deg. src role =
//     u8 hist -> nsrc + fp16 G0=nsrc*x prescale.
//   - layer_k (r10): wave=4 nodes, 16-lane group gathers 128B fp16 rows,
//     fp32 reduce, LDS stage (same-wave handoff: lgkmcnt+sched_barrier,
//     single block barrier for Ws), 64-step FMA vs LDS W, epilogue
//     ndst/bias/relu/threefry/2*nsrc; mid->fp16 G, final->fp32 out.
//   Model: layer = random-miss service floor (79MB @ ~2TB/s ~= 40us floor,
//   measured 53.5); only traffic cuts pay there (r10: -6.5% traffic ->
//   -6% time). History: r1/r8 per-feature atomics 7.5-65x write amp; r4
//   threefry hoist; r5 split; r6 slicing -- all reverted.
// ---------------------------------------------------------------------------

#define EB 2048        // edges per bin_k block
#define WGB 512        // bin_k block size
#define WGR 512        // role_k block size
#define NBK 512        // histogram capacity (>= nbuck=391)
#define NB_SHIFT 8
#define NB_W 256       // nodes per bucket
#define SUBCAP 704     // per-(bucket,xcdgrp) cap (E=512, +8.5 sigma)
#define BCAPE 5120     // per-bucket dense CSR cap (E~4476 incl pad, +10 sigma)
#define WG 256

__host__ __device__ static inline unsigned rotl32(unsigned x, int r) {
  return (x << r) | (x >> (32 - r));
}

// JAX threefry2x32 block cipher (20 rounds), matches jax/_src/prng.py lowering.
__host__ __device__ static inline void threefry2x32(unsigned k0, unsigned k1,
                                                    unsigned x0, unsigned x1,
                                                    unsigned& o0, unsigned& o1) {
  unsigned ks2 = k0 ^ k1 ^ 0x1BD11BDAu;
  x0 += k0; x1 += k1;
#define TF_ROUND(r) { x0 += x1; x1 = rotl32(x1, r); x1 ^= x0; }
  TF_ROUND(13) TF_ROUND(15) TF_ROUND(26) TF_ROUND(6)
  x0 += k1;  x1 += ks2 + 1u;
  TF_ROUND(17) TF_ROUND(29) TF_ROUND(16) TF_ROUND(24)
  x0 += ks2; x1 += k0 + 2u;
  TF_ROUND(13) TF_ROUND(15) TF_ROUND(26) TF_ROUND(6)
  x0 += k0;  x1 += k1 + 3u;
  TF_ROUND(17) TF_ROUND(29) TF_ROUND(16) TF_ROUND(24)
  x0 += k1;  x1 += ks2 + 4u;
  TF_ROUND(13) TF_ROUND(15) TF_ROUND(26) TF_ROUND(6)
  x0 += ks2; x1 += k0 + 5u;
#undef TF_ROUND
  o0 = x0; o1 = x1;
}

__device__ static inline float2 h2f(unsigned u) {
  return __half22float2(__builtin_bit_cast(__half2, u));
}
__device__ static inline unsigned f2h(float a, float b) {
  return __builtin_bit_cast(unsigned, __floats2half2_rn(a, b));
}

// ---- pass 1: dual LDS counting-sort -> dense per-(bucket,xcdgrp) sub-runs -
// dst record: (dstloc 8b << 17) | src 17b.  src record: srcloc u8.
// 512 threads on 512-entry histograms: ~1 lane/counter = conflict-free.

__global__ __launch_bounds__(WGB) void bin_k(
    const int* __restrict__ src, const int* __restrict__ dst,
    unsigned* __restrict__ binbufD, unsigned char* __restrict__ binbufS,
    int* __restrict__ cursD, int* __restrict__ cursS, int e) {
  __shared__ int hist_d[NBK], scan_d[NBK], curs_d[NBK], gpos_d[NBK];
  __shared__ int hist_s[NBK], scan_s[NBK], curs_s[NBK], gpos_s[NBK];
  __shared__ unsigned sorted_d[EB];
  __shared__ unsigned char sorted_s[EB];
  __shared__ unsigned short sbk_d[EB], sbk_s[EB];
  int tid = threadIdx.x, blk = blockIdx.x;
  int base = blk * EB;
  int cnt = e - base;
  if (cnt > EB) cnt = EB;
  int x = blk & 7;

  hist_d[tid] = 0; hist_s[tid] = 0;
  __syncthreads();
  int cnt4 = cnt & ~3;
  for (int i = tid * 4; i < cnt4; i += WGB * 4) {
    int4 d4 = *(const int4*)(dst + base + i);
    int4 s4 = *(const int4*)(src + base + i);
    atomicAdd(&hist_d[d4.x >> NB_SHIFT], 1);
    atomicAdd(&hist_d[d4.y >> NB_SHIFT], 1);
    atomicAdd(&hist_d[d4.z >> NB_SHIFT], 1);
    atomicAdd(&hist_d[d4.w >> NB_SHIFT], 1);
    atomicAdd(&hist_s[s4.x >> NB_SHIFT], 1);
    atomicAdd(&hist_s[s4.y >> NB_SHIFT], 1);
    atomicAdd(&hist_s[s4.z >> NB_SHIFT], 1);
    atomicAdd(&hist_s[s4.w >> NB_SHIFT], 1);
  }
  for (int i = cnt4 + tid; i < cnt; i += WGB) {
    atomicAdd(&hist_d[dst[base + i] >> NB_SHIFT], 1);
    atomicAdd(&hist_s[src[base + i] >> NB_SHIFT], 1);
  }
  __syncthreads();
  int hd = hist_d[tid], hs = hist_s[tid];
  scan_d[tid] = hd;
  scan_s[tid] = hs;
  __syncthreads();
  for (int st = 1; st < NBK; st <<= 1) {
    int ad = 0, as = 0;
    if (tid >= st) { ad = scan_d[tid - st]; as = scan_s[tid - st]; }
    __syncthreads();
    scan_d[tid] += ad;
    scan_s[tid] += as;
    __syncthreads();
  }
  curs_d[tid] = scan_d[tid] - hd;
  curs_s[tid] = scan_s[tid] - hs;
  __syncthreads();
  for (int i = tid * 4; i < cnt4; i += WGB * 4) {
    int4 d4 = *(const int4*)(dst + base + i);
    int4 s4 = *(const int4*)(src + base + i);
#define BIN1(dd, ss) { \
    int bd = (dd) >> NB_SHIFT; \
    int pd = atomicAdd(&curs_d[bd], 1); \
    sorted_d[pd] = ((unsigned)((dd) & (NB_W - 1)) << 17) | (unsigned)(ss); \
    sbk_d[pd] = (unsigned short)bd; \
    int bs = (ss) >> NB_SHIFT; \
    int ps = atomicAdd(&curs_s[bs], 1); \
    sorted_s[ps] = (unsigned char)((ss) & (NB_W - 1)); \
    sbk_s[ps] = (unsigned short)bs; }
    BIN1(d4.x, s4.x) BIN1(d4.y, s4.y) BIN1(d4.z, s4.z) BIN1(d4.w, s4.w)
  }
  for (int i = cnt4 + tid; i < cnt; i += WGB) {
    int d = dst[base + i];
    int s = src[base + i];
    BIN1(d, s)
  }
#undef BIN1
  __syncthreads();
  {
    int c = hist_d[tid];
    gpos_d[tid] = (c > 0) ? atomicAdd(&cursD[x * NBK + tid], c) : 0;
    c = hist_s[tid];
    gpos_s[tid] = (c > 0) ? atomicAdd(&cursS[x * NBK + tid], c) : 0;
  }
  __syncthreads();
  for (int i = tid; i < cnt; i += WGB) {
    int b = sbk_d[i];
    int gp = gpos_d[b] + (i - (scan_d[b] - hist_d[b]));
    if (gp < SUBCAP)   // overflow prob ~1e-10
      binbufD[((size_t)b * 8 + x) * SUBCAP + gp] = sorted_d[i];
    b = sbk_s[i];
    gp = gpos_s[b] + (i - (scan_s[b] - hist_s[b]));
    if (gp < SUBCAP)
      binbufS[((size_t)b * 8 + x) * SUBCAP + gp] = sorted_s[i];
  }
}

// ---- pass 2: per-bucket dense-run consumption ------------------------------
// b < nbuck: dst role -> exact bucket-local CSR (slot runs + meta).
// else: src role -> nsrc + fp16 G0 prescale.

__global__ __launch_bounds__(WGR) void role_k(
    const unsigned* __restrict__ binbufD,
    const unsigned char* __restrict__ binbufS,
    const int* __restrict__ cursD, const int* __restrict__ cursS,
    int* __restrict__ slot, unsigned* __restrict__ meta,
    float* __restrict__ nsrc, const float* __restrict__ x,
    unsigned short* __restrict__ G0, int n, int nbuck) {
  __shared__ int lcur[NB_W];
  __shared__ int loff[NB_W];
  __shared__ float lns[NB_W];
  __shared__ int cx[8];
  int tid = threadIdx.x;
  int bb = blockIdx.x;
  int role = (bb < nbuck) ? 0 : 1;
  int b = role ? (bb - nbuck) : bb;

  const int* cursX = role ? cursS : cursD;
  if (tid < 8) {
    int c = cursX[tid * NBK + b];
    cx[tid] = (c > SUBCAP) ? SUBCAP : c;
  }
  for (int i = tid; i < NB_W; i += WGR) lcur[i] = 0;
  __syncthreads();

  if (role == 0) {
    // pass A: in-degree count per bucket-local node
    for (int xx = 0; xx < 8; ++xx) {
      int c = cx[xx];
      const unsigned* sp = binbufD + ((size_t)b * 8 + xx) * SUBCAP;
      for (int i = tid; i < c; i += WGR) atomicAdd(&lcur[sp[i] >> 17], 1);
    }
    __syncthreads();
    // exclusive scan of 4-padded counts -> bucket-local CSR offsets
    int c4 = 0;
    if (tid < NB_W) { c4 = (lcur[tid] + 3) & ~3; loff[tid] = c4; }
    __syncthreads();
    for (int st = 1; st < NB_W; st <<= 1) {
      int a = 0;
      if (tid < NB_W && tid >= st) a = loff[tid - st];
      __syncthreads();
      if (tid < NB_W) loff[tid] += a;
      __syncthreads();
    }
    if (tid < NB_W) {
      int off = loff[tid] - c4;          // exclusive
      loff[tid] = off;
      int v = (b << NB_SHIFT) + tid;
      if (v < n) {
        int dg = lcur[tid]; if (dg > 255) dg = 255;
        unsigned of = (off < BCAPE) ? (unsigned)off : 0u;
        meta[v] = (of << 8) | (unsigned)dg;
      }
    }
    __syncthreads();
    for (int i = tid; i < NB_W; i += WGR) lcur[i] = 0;
    __syncthreads();
    // pass B: scatter edges to dense bucket-local CSR (runs L2-hot)
    size_t sbase = (size_t)b * BCAPE;
    for (int xx = 0; xx < 8; ++xx) {
      int c = cx[xx];
      const unsigned* sp = binbufD + ((size_t)b * 8 + xx) * SUBCAP;
      for (int i = tid; i < c; i += WGR) {
        unsigned vv = sp[i];
        int dl = vv >> 17;
        int s = (int)(vv & 0x1FFFFu);
        int cc = atomicAdd(&lcur[dl], 1);
        int p = loff[dl] + cc;
        if (p < BCAPE) slot[sbase + p] = s;
      }
    }
  } else {
    // src role: u8 srcloc hist -> nsrc + fp16 G0 = nsrc*x prescale
    for (int xx = 0; xx < 8; ++xx) {
      int c = cx[xx];
      const unsigned char* sp = binbufS + ((size_t)b * 8 + xx) * SUBCAP;
      for (int i = tid; i < c; i += WGR) atomicAdd(&lcur[sp[i]], 1);
    }
    __syncthreads();
    int vbase = b << NB_SHIFT;
    for (int i = tid; i < NB_W; i += WGR) {
      int v = vbase + i;
      if (v < n) {
        int c = lcur[i];
        float ns = (c > 0) ? rsqrtf((float)c) : 0.f;
        lns[i] = ns;
        nsrc[v] = ns;
      }
    }
    __syncthreads();
    const float4* x4 = (const float4*)x;
    uint2* G2 = (uint2*)G0;
    for (int idx = tid; idx < NB_W * 16; idx += WGR) {
      int i = idx >> 4;
      int v = vbase + i;
      if (v < n) {
        float ns = lns[i];
        float4 r = x4[(size_t)v * 16 + (idx & 15)];
        G2[(size_t)v * 16 + (idx & 15)] =
            make_uint2(f2h(r.x * ns, r.y * ns), f2h(r.z * ns, r.w * ns));
      }
    }
  }
}

// ---- fused per-layer kernel: fp16 gather -> fp32 @W -> epilogue -----------
// Wave = 4 nodes (16-lane group per node). Dense CSR: meta[v]=(off<<8)|deg,
// slot run at slot[(v>>8)*BCAPE + off]. Single barrier (Ws staging) before
// gather; rows hand-off is same-wave -> lgkmcnt(0)+sched_barrier only.
__global__ __launch_bounds__(WG) void layer_k(
    const unsigned short* __restrict__ G, const int* __restrict__ slot,
    const unsigned* __restrict__ meta, const float* __restrict__ nsrc,
    const float* __restrict__ W, const float* __restrict__ bias,
    unsigned short* __restrict__ GoutH, float* __restrict__ GoutF,
    int n, int mid, unsigned dk0, unsigned dk1) {
  __shared__ float4 Ws[1024];                  // 16 KB W[k][j]
  __shared__ __align__(16) float rows[4][272]; // 4 waves x (4 rows @ 68)
  const float4* W4 = (const float4*)W;
  for (int i = threadIdx.x; i < 1024; i += WG) Ws[i] = W4[i];
  __syncthreads();   // Ws visible to all waves; only barrier in the kernel

  int wave = threadIdx.x >> 6;
  int lane = threadIdx.x & 63;
  int g = lane >> 4;
  int l16 = lane & 15;
  int v = blockIdx.x * 16 + wave * 4 + g;
  bool valid = (v < n);
  int vc = valid ? v : (n - 1);

  unsigned mt = meta[vc];
  int degt = valid ? (int)(mt & 255u) : 0;
  int deg = degt;
  const int* sl = slot + (size_t)(vc >> NB_SHIFT) * BCAPE + (mt >> 8);
  const uint2* G2 = (const uint2*)G;

  float4 aA = make_float4(0.f, 0.f, 0.f, 0.f);
  float4 aB = make_float4(0.f, 0.f, 0.f, 0.f);
  float4 aC = make_float4(0.f, 0.f, 0.f, 0.f);
  float4 aD = make_float4(0.f, 0.f, 0.f, 0.f);
#define ACC(dst, m) { float2 lo = h2f((m).x), hi = h2f((m).y); \
    dst.x += lo.x; dst.y += lo.y; dst.z += hi.x; dst.w += hi.y; }
  int nq = deg >> 2;
  int i = 0;
  for (; i + 1 < nq; i += 2) {   // 2 quads = 8 gathers in flight per group
    int4 q0 = *(const int4*)(sl + i * 4);
    int4 q1 = *(const int4*)(sl + i * 4 + 4);
    uint2 m0 = G2[(size_t)q0.x * 16 + l16];
    uint2 m1 = G2[(size_t)q0.y * 16 + l16];
    uint2 m2 = G2[(size_t)q0.z * 16 + l16];
    uint2 m3 = G2[(size_t)q0.w * 16 + l16];
    uint2 m4 = G2[(size_t)q1.x * 16 + l16];
    uint2 m5 = G2[(size_t)q1.y * 16 + l16];
    uint2 m6 = G2[(size_t)q1.z * 16 + l16];
    uint2 m7 = G2[(size_t)q1.w * 16 + l16];
    ACC(aA, m0) ACC(aB, m1) ACC(aC, m2) ACC(aD, m3)
    ACC(aA, m4) ACC(aB, m5) ACC(aC, m6) ACC(aD, m7)
  }
  if (i < nq) {
    int4 q0 = *(const int4*)(sl + i * 4);
    uint2 m0 = G2[(size_t)q0.x * 16 + l16];
    uint2 m1 = G2[(size_t)q0.y * 16 + l16];
    uint2 m2 = G2[(size_t)q0.z * 16 + l16];
    uint2 m3 = G2[(size_t)q0.w * 16 + l16];
    ACC(aA, m0) ACC(aB, m1) ACC(aC, m2) ACC(aD, m3)
  }
  int rem = deg & 3;
  if (rem) {   // fma-masked tail quad; run 4-padded -> memory-safe
    int4 qq = *(const int4*)(sl + (deg & ~3));
    int s0 = qq.x;                        // rem >= 1
    int s1 = (rem > 1) ? qq.y : s0;
    int s2 = (rem > 2) ? qq.z : s0;
    float w1 = (rem > 1) ? 1.f : 0.f;
    float w2 = (rem > 2) ? 1.f : 0.f;
    uint2 m0 = G2[(size_t)s0 * 16 + l16];
    uint2 m1 = G2[(size_t)s1 * 16 + l16];
    uint2 m2 = G2[(size_t)s2 * 16 + l16];
    ACC(aA, m0)
    { float2 lo = h2f(m1.x), hi = h2f(m1.y);
      aB.x = fmaf(w1, lo.x, aB.x); aB.y = fmaf(w1, lo.y, aB.y);
      aB.z = fmaf(w1, hi.x, aB.z); aB.w = fmaf(w1, hi.y, aB.w); }
    { float2 lo = h2f(m2.x), hi = h2f(m2.y);
      aC.x = fmaf(w2, lo.x, aC.x); aC.y = fmaf(w2, lo.y, aC.y);
      aC.z = fmaf(w2, hi.x, aC.z); aC.w = fmaf(w2, hi.y, aC.w); }
  }
#undef ACC
  float4 agg;
  agg.x = (aA.x + aB.x) + (aC.x + aD.x);
  agg.y = (aA.y + aB.y) + (aC.y + aD.y);
  agg.z = (aA.z + aB.z) + (aC.z + aD.z);
  agg.w = (aA.w + aB.w) + (aC.w + aD.w);

  float* rw = &rows[wave][g * 68];
  *(float4*)(rw + l16 * 4) = agg;
  // same-wave LDS hand-off: lockstep + lgkmcnt(0) suffices (no __syncthreads)
  asm volatile("s_waitcnt lgkmcnt(0)" ::: "memory");
  __builtin_amdgcn_sched_barrier(0);

  float4 acc = make_float4(0.f, 0.f, 0.f, 0.f);
#pragma unroll
  for (int k = 0; k < 64; ++k) {
    float a = rw[k];
    float4 w = Ws[k * 16 + l16];
    acc.x = fmaf(a, w.x, acc.x);
    acc.y = fmaf(a, w.y, acc.y);
    acc.z = fmaf(a, w.z, acc.z);
    acc.w = fmaf(a, w.w, acc.w);
  }

  float nd = (degt > 0) ? rsqrtf((float)degt) : 0.f;
  float4 b4 = ((const float4*)bias)[l16];
  float4 o;
  o.x = fmaf(acc.x, nd, b4.x);
  o.y = fmaf(acc.y, nd, b4.y);
  o.z = fmaf(acc.z, nd, b4.z);
  o.w = fmaf(acc.w, nd, b4.w);
  if (mid) {
    o.x = fmaxf(o.x, 0.f); o.y = fmaxf(o.y, 0.f);
    o.z = fmaxf(o.z, 0.f); o.w = fmaxf(o.w, 0.f);
    unsigned idx = (unsigned)(v * 64 + l16 * 4);
    unsigned r0a, r0b, r1a, r1b, r2a, r2b, r3a, r3b;
    threefry2x32(dk0, dk1, 0u, idx + 0u, r0a, r0b);
    threefry2x32(dk0, dk1, 0u, idx + 1u, r1a, r1b);
    threefry2x32(dk0, dk1, 0u, idx + 2u, r2a, r2b);
    threefry2x32(dk0, dk1, 0u, idx + 3u, r3a, r3b);
    float ns2 = 2.f * nsrc[vc];   // dropout keep-scale x next-layer nsrc
    o.x = ((r0a ^ r0b) & 0x80000000u) ? 0.f : o.x * ns2;
    o.y = ((r1a ^ r1b) & 0x80000000u) ? 0.f : o.y * ns2;
    o.z = ((r2a ^ r2b) & 0x80000000u) ? 0.f : o.z * ns2;
    o.w = ((r3a ^ r3b) & 0x80000000u) ? 0.f : o.w * ns2;
    if (valid)
      ((uint2*)GoutH)[(size_t)v * 16 + l16] =
          make_uint2(f2h(o.x, o.y), f2h(o.z, o.w));
  } else {
    if (valid) ((float4*)GoutF)[(size_t)v * 16 + l16] = o;
  }
}

// ---------------------------------------------------------------------------

extern "C" void kernel_launch(void* const* d_in, const int* in_sizes, int n_in,
                              void* d_out, int out_size, void* d_ws, size_t ws_size,
                              hipStream_t stream) {
  const float* x  = (const float*)d_in[0];
  const float* W0 = (const float*)d_in[1];
  const float* b0 = (const float*)d_in[2];
  const float* W1 = (const float*)d_in[3];
  const float* b1 = (const float*)d_in[4];
  const float* W2 = (const float*)d_in[5];
  const float* b2 = (const float*)d_in[6];
  const int* src  = (const int*)d_in[7];
  const int* dst  = (const int*)d_in[8];
  float* out = (float*)d_out;

  const int n = in_sizes[0] / 64;   // 100000
  const int e = in_sizes[7];        // 1600000
  const int nbuck = (n + NB_W - 1) / NB_W;   // 391
  const int nblk = (e + EB - 1) / EB;        // 782

  char* w = (char*)d_ws;
  size_t off = 0;
  auto alloc = [&](size_t bytes) -> void* {
    void* p = w + off;
    off += (bytes + 255) & ~(size_t)255;
    return p;
  };
  unsigned*       meta    = (unsigned*)alloc((size_t)n * 4);
  float*          nsrc    = (float*)alloc((size_t)n * 4);
  int*            cursD   = (int*)alloc((size_t)8 * NBK * 4);
  int*            cursS   = (int*)alloc((size_t)8 * NBK * 4);
  unsigned*       binbufD = (unsigned*)alloc((size_t)nbuck * 8 * SUBCAP * 4); // 8.8 MB
  unsigned char*  binbufS = (unsigned char*)alloc((size_t)nbuck * 8 * SUBCAP); // 2.2 MB
  int*            slot    = (int*)alloc((size_t)nbuck * BCAPE * 4);           // 8.0 MB
  unsigned short* G0      = (unsigned short*)alloc((size_t)n * 64 * 2);       // 12.8 MB
  unsigned short* G1      = (unsigned short*)alloc((size_t)n * 64 * 2);       // 12.8 MB

  unsigned k0a, k0b, k1a, k1b;
  threefry2x32(0u, 1u, 0u, 0u, k0a, k0b);
  threefry2x32(0u, 1u, 0u, 1u, k1a, k1b);

  const int gL = (n + 15) / 16;   // layer: 16 nodes/block

  hipMemsetAsync(cursD, 0, (size_t)8 * NBK * 4, stream);
  hipMemsetAsync(cursS, 0, (size_t)8 * NBK * 4, stream);

  bin_k<<<nblk, WGB, 0, stream>>>(src, dst, binbufD, binbufS,
                                  cursD, cursS, e);
  role_k<<<2 * nbuck, WGR, 0, stream>>>(binbufD, binbufS, cursD, cursS,
                                        slot, meta, nsrc, x, G0, n, nbuck);

  // layer 0: gather G0 -> fp16 G1   (relu+drop key0, x 2*nsrc)
  layer_k<<<gL, WG, 0, stream>>>(G0, slot, meta, nsrc, W0, b0, G1, nullptr,
                                 n, 1, k0a, k0b);
  // layer 1: gather G1 -> fp16 G0   (relu+drop key1, x 2*nsrc)
  layer_k<<<gL, WG, 0, stream>>>(G1, slot, meta, nsrc, W1, b1, G0, nullptr,
                                 n, 1, k1a, k1b);
  // layer 2: gather G0 -> fp32 d_out (final, no epilogue extras)
  layer_k<<<gL, WG, 0, stream>>>(G0, slot, meta, nsrc, W2, b2, nullptr, out,
                                 n, 0, 0u, 0u);
}

// Round 12
// 262.268 us; speedup vs baseline: 1.0141x; 1.0141x over previous
//
#include <hip/hip_runtime.h>
#include <hip/hip_bf16.h>
#include <hip/hip_fp16.h>
#include <cstddef>

// ---------------------------------------------------------------------------
// GCN: 3x GraphConv(norm='both') + relu + threefry dropout (p=0.5)
//   Aggregate-first identity: ndst (A (nsrc.h) W) == ndst (A (nsrc.h)) W.
//   Gather buffers G are FP16 row-major; all accumulation stays FP32.
//
//   r12 = exact revert to r10 (best measured, 261.5us). r11's fine buckets
//   (NB_W 256) were neutral-to-negative -> preproc LDS-atomic-conflict
//   theory falsified; preprocessing is latency-floor-bound (~100us,
//   invariant across 5 structural variants). Final structure:
//   1) EXACT bucket-local CSR slot: 4-padded offsets, meta[v]=(off<<8)|deg,
//      dense slot runs (slot 8MB). Cut layer FETCH 84.6->79.1MB.
//   2) binbufS u16 (src role only needs srcloc).
//   3) layer_k: single barrier after Ws staging; rows LDS hand-off is
//      same-wave only -> s_waitcnt lgkmcnt(0)+sched_barrier.
//   Model (r4-r11): layer = random-miss service floor: 79MB fetch +
//   12.5MB write @ ~1.75TB/s ~= 53us. Only traffic cuts pay (r10: -6.5%
//   traffic -> -6% time); occupancy/VALU/structure all null. Preproc =
//   sort latency floor (~100us across NB_W 512/256, wave-coop/lane-serial,
//   dense/sliced). History: r1/r8 per-feature global atomics = 7.5-65x
//   write amp; r4 threefry hoist serialized; r5 split neutral; r6 slicing
//   traded G residency for slot re-read; r8 push-mode 65x write amp.
// ---------------------------------------------------------------------------

#define EB 4096        // edges per bin_k block
#define SUBCAP 1280    // per-(bucket,xcdgroup) sub-run cap (E=1020, +8 sigma)
#define NB_SHIFT 9
#define NB_W 512       // nodes per bucket
#define BCAPE 10240    // per-bucket dense CSR capacity (E=8163+pad, +14 sigma)
#define WG 256

__host__ __device__ static inline unsigned rotl32(unsigned x, int r) {
  return (x << r) | (x >> (32 - r));
}

// JAX threefry2x32 block cipher (20 rounds), matches jax/_src/prng.py lowering.
__host__ __device__ static inline void threefry2x32(unsigned k0, unsigned k1,
                                                    unsigned x0, unsigned x1,
                                                    unsigned& o0, unsigned& o1) {
  unsigned ks2 = k0 ^ k1 ^ 0x1BD11BDAu;
  x0 += k0; x1 += k1;
#define TF_ROUND(r) { x0 += x1; x1 = rotl32(x1, r); x1 ^= x0; }
  TF_ROUND(13) TF_ROUND(15) TF_ROUND(26) TF_ROUND(6)
  x0 += k1;  x1 += ks2 + 1u;
  TF_ROUND(17) TF_ROUND(29) TF_ROUND(16) TF_ROUND(24)
  x0 += ks2; x1 += k0 + 2u;
  TF_ROUND(13) TF_ROUND(15) TF_ROUND(26) TF_ROUND(6)
  x0 += k0;  x1 += k1 + 3u;
  TF_ROUND(17) TF_ROUND(29) TF_ROUND(16) TF_ROUND(24)
  x0 += k1;  x1 += ks2 + 4u;
  TF_ROUND(13) TF_ROUND(15) TF_ROUND(26) TF_ROUND(6)
  x0 += ks2; x1 += k0 + 5u;
#undef TF_ROUND
  o0 = x0; o1 = x1;
}

__device__ static inline float2 h2f(unsigned u) {
  return __half22float2(__builtin_bit_cast(__half2, u));
}
__device__ static inline unsigned f2h(float a, float b) {
  return __builtin_bit_cast(unsigned, __floats2half2_rn(a, b));
}

// ---- pass 1: dual LDS counting-sort -> dense per-(bucket,xcdgrp) sub-runs -
// dst record: (dstloc 9b << 17) | src 17b.  src record: srcloc u16.

__global__ __launch_bounds__(1024) void bin_k(
    const int* __restrict__ src, const int* __restrict__ dst,
    unsigned* __restrict__ binbufD, unsigned short* __restrict__ binbufS,
    int* __restrict__ cursD, int* __restrict__ cursS, int e) {
  __shared__ int hist_d[256], scan_d[256], curs_d[256], gpos_d[256];
  __shared__ int hist_s[256], scan_s[256], curs_s[256], gpos_s[256];
  __shared__ unsigned sorted_d[EB];
  __shared__ unsigned short sorted_s[EB];
  __shared__ unsigned char sbk_d[EB], sbk_s[EB];
  int tid = threadIdx.x, blk = blockIdx.x;
  int base = blk * EB;
  int cnt = e - base;
  if (cnt > EB) cnt = EB;
  int x = blk & 7;

  if (tid < 256) { hist_d[tid] = 0; hist_s[tid] = 0; }
  __syncthreads();
  for (int i = tid; i < cnt; i += 1024) {
    atomicAdd(&hist_d[dst[base + i] >> NB_SHIFT], 1);
    atomicAdd(&hist_s[src[base + i] >> NB_SHIFT], 1);
  }
  __syncthreads();
  int hd = 0, hs = 0;
  if (tid < 256) {
    hd = hist_d[tid]; scan_d[tid] = hd;
    hs = hist_s[tid]; scan_s[tid] = hs;
  }
  __syncthreads();
  for (int st = 1; st < 256; st <<= 1) {
    int ad = 0, as = 0;
    if (tid < 256 && tid >= st) { ad = scan_d[tid - st]; as = scan_s[tid - st]; }
    __syncthreads();
    if (tid < 256) { scan_d[tid] += ad; scan_s[tid] += as; }
    __syncthreads();
  }
  if (tid < 256) { curs_d[tid] = scan_d[tid] - hd; curs_s[tid] = scan_s[tid] - hs; }
  __syncthreads();
  for (int i = tid; i < cnt; i += 1024) {
    int s = src[base + i];
    int d = dst[base + i];
    int bd = d >> NB_SHIFT;
    int pd = atomicAdd(&curs_d[bd], 1);
    sorted_d[pd] = ((unsigned)(d & (NB_W - 1)) << 17) | (unsigned)s;
    sbk_d[pd] = (unsigned char)bd;
    int bs = s >> NB_SHIFT;
    int ps = atomicAdd(&curs_s[bs], 1);
    sorted_s[ps] = (unsigned short)(s & (NB_W - 1));
    sbk_s[ps] = (unsigned char)bs;
  }
  __syncthreads();
  if (tid < 256) {
    int c = hist_d[tid];
    gpos_d[tid] = (c > 0) ? atomicAdd(&cursD[x * 256 + tid], c) : 0;
    c = hist_s[tid];
    gpos_s[tid] = (c > 0) ? atomicAdd(&cursS[x * 256 + tid], c) : 0;
  }
  __syncthreads();
  for (int i = tid; i < cnt; i += 1024) {
    int b = sbk_d[i];
    int gp = gpos_d[b] + (i - (scan_d[b] - hist_d[b]));
    if (gp < SUBCAP)   // overflow prob ~1e-10
      binbufD[((size_t)b * 8 + x) * SUBCAP + gp] = sorted_d[i];
    b = sbk_s[i];
    gp = gpos_s[b] + (i - (scan_s[b] - hist_s[b]));
    if (gp < SUBCAP)
      binbufS[((size_t)b * 8 + x) * SUBCAP + gp] = sorted_s[i];
  }
}

// ---- pass 2: per-bucket dense-run consumption ------------------------------
// b < nbuck: dst role -> dense bucket-local CSR (slot runs + meta).
// else: src role -> nsrc + fp16 G0 prescale.

__global__ __launch_bounds__(1024) void role_k(
    const unsigned* __restrict__ binbufD,
    const unsigned short* __restrict__ binbufS,
    const int* __restrict__ cursD, const int* __restrict__ cursS,
    int* __restrict__ slot, unsigned* __restrict__ meta,
    float* __restrict__ nsrc, const float* __restrict__ x,
    unsigned short* __restrict__ G0, int n, int nbuck) {
  __shared__ int lcur[NB_W];
  __shared__ int loff[NB_W];
  __shared__ float lns[NB_W];
  __shared__ int cx[8];
  int tid = threadIdx.x;
  int bb = blockIdx.x;
  int role = (bb < nbuck) ? 0 : 1;
  int b = role ? (bb - nbuck) : bb;

  const int* cursX = role ? cursS : cursD;
  if (tid < 8) {
    int c = cursX[tid * 256 + b];
    cx[tid] = (c > SUBCAP) ? SUBCAP : c;
  }
  for (int i = tid; i < NB_W; i += 1024) lcur[i] = 0;
  __syncthreads();

  if (role == 0) {
    // pass A: in-degree count per bucket-local node
    for (int xx = 0; xx < 8; ++xx) {
      int c = cx[xx];
      const unsigned* sp = binbufD + ((size_t)b * 8 + xx) * SUBCAP;
      for (int i = tid; i < c; i += 1024) atomicAdd(&lcur[sp[i] >> 17], 1);
    }
    __syncthreads();
    // exclusive scan of 4-padded counts -> bucket-local CSR offsets
    int c4 = 0;
    if (tid < NB_W) { c4 = (lcur[tid] + 3) & ~3; loff[tid] = c4; }
    __syncthreads();
    for (int st = 1; st < NB_W; st <<= 1) {
      int a = 0;
      if (tid < NB_W && tid >= st) a = loff[tid - st];
      __syncthreads();
      if (tid < NB_W) loff[tid] += a;
      __syncthreads();
    }
    if (tid < NB_W) {
      int off = loff[tid] - c4;          // exclusive
      loff[tid] = off;
      int v = (b << NB_SHIFT) + tid;
      if (v < n) {
        int dg = lcur[tid]; if (dg > 255) dg = 255;
        unsigned of = (off < BCAPE) ? (unsigned)off : 0u;
        meta[v] = (of << 8) | (unsigned)dg;
      }
    }
    __syncthreads();
    for (int i = tid; i < NB_W; i += 1024) lcur[i] = 0;
    __syncthreads();
    // pass B: scatter edges to dense bucket-local CSR (runs L2-hot)
    size_t sbase = (size_t)b * BCAPE;
    for (int xx = 0; xx < 8; ++xx) {
      int c = cx[xx];
      const unsigned* sp = binbufD + ((size_t)b * 8 + xx) * SUBCAP;
      for (int i = tid; i < c; i += 1024) {
        unsigned vv = sp[i];
        int dl = vv >> 17;
        int s = (int)(vv & 0x1FFFFu);
        int cc = atomicAdd(&lcur[dl], 1);
        int p = loff[dl] + cc;
        if (p < BCAPE) slot[sbase + p] = s;
      }
    }
  } else {
    // src role: u16 srcloc hist -> nsrc + fp16 G0 = nsrc*x prescale
    for (int xx = 0; xx < 8; ++xx) {
      int c = cx[xx];
      const unsigned short* sp = binbufS + ((size_t)b * 8 + xx) * SUBCAP;
      for (int i = tid; i < c; i += 1024) atomicAdd(&lcur[sp[i]], 1);
    }
    __syncthreads();
    int vbase = b << NB_SHIFT;
    for (int i = tid; i < NB_W; i += 1024) {
      int v = vbase + i;
      if (v < n) {
        int c = lcur[i];
        float ns = (c > 0) ? rsqrtf((float)c) : 0.f;
        lns[i] = ns;
        nsrc[v] = ns;
      }
    }
    __syncthreads();
    const float4* x4 = (const float4*)x;
    uint2* G2 = (uint2*)G0;
    for (int idx = tid; idx < NB_W * 16; idx += 1024) {
      int i = idx >> 4;
      int v = vbase + i;
      if (v < n) {
        float ns = lns[i];
        float4 r = x4[(size_t)v * 16 + (idx & 15)];
        G2[(size_t)v * 16 + (idx & 15)] =
            make_uint2(f2h(r.x * ns, r.y * ns), f2h(r.z * ns, r.w * ns));
      }
    }
  }
}

// ---- fused per-layer kernel: fp16 gather -> fp32 @W -> epilogue -----------
// Wave = 4 nodes (16-lane group per node). Dense CSR: meta[v]=(off<<8)|deg,
// slot run at slot[(v>>9)*BCAPE + off]. Single barrier (Ws staging) before
// gather; rows hand-off is same-wave -> lgkmcnt(0)+sched_barrier only, so
// waves decouple after their own gather.
__global__ __launch_bounds__(WG) void layer_k(
    const unsigned short* __restrict__ G, const int* __restrict__ slot,
    const unsigned* __restrict__ meta, const float* __restrict__ nsrc,
    const float* __restrict__ W, const float* __restrict__ bias,
    unsigned short* __restrict__ GoutH, float* __restrict__ GoutF,
    int n, int mid, unsigned dk0, unsigned dk1) {
  __shared__ float4 Ws[1024];                  // 16 KB W[k][j]
  __shared__ __align__(16) float rows[4][272]; // 4 waves x (4 rows @ 68)
  const float4* W4 = (const float4*)W;
  for (int i = threadIdx.x; i < 1024; i += WG) Ws[i] = W4[i];
  __syncthreads();   // Ws visible to all waves; only barrier in the kernel

  int wave = threadIdx.x >> 6;
  int lane = threadIdx.x & 63;
  int g = lane >> 4;
  int l16 = lane & 15;
  int v = blockIdx.x * 16 + wave * 4 + g;
  bool valid = (v < n);
  int vc = valid ? v : (n - 1);

  unsigned mt = meta[vc];
  int degt = valid ? (int)(mt & 255u) : 0;
  int deg = degt;
  const int* sl = slot + (size_t)(vc >> NB_SHIFT) * BCAPE + (mt >> 8);
  const uint2* G2 = (const uint2*)G;

  float4 aA = make_float4(0.f, 0.f, 0.f, 0.f);
  float4 aB = make_float4(0.f, 0.f, 0.f, 0.f);
  float4 aC = make_float4(0.f, 0.f, 0.f, 0.f);
  float4 aD = make_float4(0.f, 0.f, 0.f, 0.f);
#define ACC(dst, m) { float2 lo = h2f((m).x), hi = h2f((m).y); \
    dst.x += lo.x; dst.y += lo.y; dst.z += hi.x; dst.w += hi.y; }
  int nq = deg >> 2;
  int i = 0;
  for (; i + 1 < nq; i += 2) {   // 2 quads = 8 gathers in flight per group
    int4 q0 = *(const int4*)(sl + i * 4);
    int4 q1 = *(const int4*)(sl + i * 4 + 4);
    uint2 m0 = G2[(size_t)q0.x * 16 + l16];
    uint2 m1 = G2[(size_t)q0.y * 16 + l16];
    uint2 m2 = G2[(size_t)q0.z * 16 + l16];
    uint2 m3 = G2[(size_t)q0.w * 16 + l16];
    uint2 m4 = G2[(size_t)q1.x * 16 + l16];
    uint2 m5 = G2[(size_t)q1.y * 16 + l16];
    uint2 m6 = G2[(size_t)q1.z * 16 + l16];
    uint2 m7 = G2[(size_t)q1.w * 16 + l16];
    ACC(aA, m0) ACC(aB, m1) ACC(aC, m2) ACC(aD, m3)
    ACC(aA, m4) ACC(aB, m5) ACC(aC, m6) ACC(aD, m7)
  }
  if (i < nq) {
    int4 q0 = *(const int4*)(sl + i * 4);
    uint2 m0 = G2[(size_t)q0.x * 16 + l16];
    uint2 m1 = G2[(size_t)q0.y * 16 + l16];
    uint2 m2 = G2[(size_t)q0.z * 16 + l16];
    uint2 m3 = G2[(size_t)q0.w * 16 + l16];
    ACC(aA, m0) ACC(aB, m1) ACC(aC, m2) ACC(aD, m3)
  }
  int rem = deg & 3;
  if (rem) {   // fma-masked tail quad; run 4-padded -> memory-safe
    int4 qq = *(const int4*)(sl + (deg & ~3));
    int s0 = qq.x;                        // rem >= 1
    int s1 = (rem > 1) ? qq.y : s0;
    int s2 = (rem > 2) ? qq.z : s0;
    float w1 = (rem > 1) ? 1.f : 0.f;
    float w2 = (rem > 2) ? 1.f : 0.f;
    uint2 m0 = G2[(size_t)s0 * 16 + l16];
    uint2 m1 = G2[(size_t)s1 * 16 + l16];
    uint2 m2 = G2[(size_t)s2 * 16 + l16];
    ACC(aA, m0)
    { float2 lo = h2f(m1.x), hi = h2f(m1.y);
      aB.x = fmaf(w1, lo.x, aB.x); aB.y = fmaf(w1, lo.y, aB.y);
      aB.z = fmaf(w1, hi.x, aB.z); aB.w = fmaf(w1, hi.y, aB.w); }
    { float2 lo = h2f(m2.x), hi = h2f(m2.y);
      aC.x = fmaf(w2, lo.x, aC.x); aC.y = fmaf(w2, lo.y, aC.y);
      aC.z = fmaf(w2, hi.x, aC.z); aC.w = fmaf(w2, hi.y, aC.w); }
  }
#undef ACC
  float4 agg;
  agg.x = (aA.x + aB.x) + (aC.x + aD.x);
  agg.y = (aA.y + aB.y) + (aC.y + aD.y);
  agg.z = (aA.z + aB.z) + (aC.z + aD.z);
  agg.w = (aA.w + aB.w) + (aC.w + aD.w);

  float* rw = &rows[wave][g * 68];
  *(float4*)(rw + l16 * 4) = agg;
  // same-wave LDS hand-off: lockstep + lgkmcnt(0) suffices (no __syncthreads)
  asm volatile("s_waitcnt lgkmcnt(0)" ::: "memory");
  __builtin_amdgcn_sched_barrier(0);

  float4 acc = make_float4(0.f, 0.f, 0.f, 0.f);
#pragma unroll
  for (int k = 0; k < 64; ++k) {
    float a = rw[k];
    float4 w = Ws[k * 16 + l16];
    acc.x = fmaf(a, w.x, acc.x);
    acc.y = fmaf(a, w.y, acc.y);
    acc.z = fmaf(a, w.z, acc.z);
    acc.w = fmaf(a, w.w, acc.w);
  }

  float nd = (degt > 0) ? rsqrtf((float)degt) : 0.f;
  float4 b4 = ((const float4*)bias)[l16];
  float4 o;
  o.x = fmaf(acc.x, nd, b4.x);
  o.y = fmaf(acc.y, nd, b4.y);
  o.z = fmaf(acc.z, nd, b4.z);
  o.w = fmaf(acc.w, nd, b4.w);
  if (mid) {
    o.x = fmaxf(o.x, 0.f); o.y = fmaxf(o.y, 0.f);
    o.z = fmaxf(o.z, 0.f); o.w = fmaxf(o.w, 0.f);
    unsigned idx = (unsigned)(v * 64 + l16 * 4);
    unsigned r0a, r0b, r1a, r1b, r2a, r2b, r3a, r3b;
    threefry2x32(dk0, dk1, 0u, idx + 0u, r0a, r0b);
    threefry2x32(dk0, dk1, 0u, idx + 1u, r1a, r1b);
    threefry2x32(dk0, dk1, 0u, idx + 2u, r2a, r2b);
    threefry2x32(dk0, dk1, 0u, idx + 3u, r3a, r3b);
    float ns2 = 2.f * nsrc[vc];   // dropout keep-scale x next-layer nsrc
    o.x = ((r0a ^ r0b) & 0x80000000u) ? 0.f : o.x * ns2;
    o.y = ((r1a ^ r1b) & 0x80000000u) ? 0.f : o.y * ns2;
    o.z = ((r2a ^ r2b) & 0x80000000u) ? 0.f : o.z * ns2;
    o.w = ((r3a ^ r3b) & 0x80000000u) ? 0.f : o.w * ns2;
    if (valid)
      ((uint2*)GoutH)[(size_t)v * 16 + l16] =
          make_uint2(f2h(o.x, o.y), f2h(o.z, o.w));
  } else {
    if (valid) ((float4*)GoutF)[(size_t)v * 16 + l16] = o;
  }
}

// ---------------------------------------------------------------------------

extern "C" void kernel_launch(void* const* d_in, const int* in_sizes, int n_in,
                              void* d_out, int out_size, void* d_ws, size_t ws_size,
                              hipStream_t stream) {
  const float* x  = (const float*)d_in[0];
  const float* W0 = (const float*)d_in[1];
  const float* b0 = (const float*)d_in[2];
  const float* W1 = (const float*)d_in[3];
  const float* b1 = (const float*)d_in[4];
  const float* W2 = (const float*)d_in[5];
  const float* b2 = (const float*)d_in[6];
  const int* src  = (const int*)d_in[7];
  const int* dst  = (const int*)d_in[8];
  float* out = (float*)d_out;

  const int n = in_sizes[0] / 64;   // 100000
  const int e = in_sizes[7];        // 1600000
  const int nbuck = (n + NB_W - 1) / NB_W;   // 196
  const int nblk = (e + EB - 1) / EB;        // 391

  char* w = (char*)d_ws;
  size_t off = 0;
  auto alloc = [&](size_t bytes) -> void* {
    void* p = w + off;
    off += (bytes + 255) & ~(size_t)255;
    return p;
  };
  unsigned*       meta    = (unsigned*)alloc((size_t)n * 4);
  float*          nsrc    = (float*)alloc((size_t)n * 4);
  int*            cursD   = (int*)alloc((size_t)8 * 256 * 4);
  int*            cursS   = (int*)alloc((size_t)8 * 256 * 4);
  unsigned*       binbufD = (unsigned*)alloc((size_t)nbuck * 8 * SUBCAP * 4); // 8.0 MB
  unsigned short* binbufS = (unsigned short*)alloc((size_t)nbuck * 8 * SUBCAP * 2); // 4.0 MB
  int*            slot    = (int*)alloc((size_t)nbuck * BCAPE * 4);           // 8.0 MB
  unsigned short* G0      = (unsigned short*)alloc((size_t)n * 64 * 2);       // 12.8 MB
  unsigned short* G1      = (unsigned short*)alloc((size_t)n * 64 * 2);       // 12.8 MB

  unsigned k0a, k0b, k1a, k1b;
  threefry2x32(0u, 1u, 0u, 0u, k0a, k0b);
  threefry2x32(0u, 1u, 0u, 1u, k1a, k1b);

  const int gL = (n + 15) / 16;   // layer: 16 nodes/block

  hipMemsetAsync(cursD, 0, (size_t)8 * 256 * 4, stream);
  hipMemsetAsync(cursS, 0, (size_t)8 * 256 * 4, stream);

  bin_k<<<nblk, 1024, 0, stream>>>(src, dst, binbufD, binbufS,
                                   cursD, cursS, e);
  role_k<<<2 * nbuck, 1024, 0, stream>>>(binbufD, binbufS, cursD, cursS,
                                         slot, meta, nsrc, x, G0, n, nbuck);

  // layer 0: gather G0 -> fp16 G1   (relu+drop key0, x 2*nsrc)
  layer_k<<<gL, WG, 0, stream>>>(G0, slot, meta, nsrc, W0, b0, G1, nullptr,
                                 n, 1, k0a, k0b);
  // layer 1: gather G1 -> fp16 G0   (relu+drop key1, x 2*nsrc)
  layer_k<<<gL, WG, 0, stream>>>(G1, slot, meta, nsrc, W1, b1, G0, nullptr,
                                 n, 1, k1a, k1b);
  // layer 2: gather G0 -> fp32 d_out (final, no epilogue extras)
  layer_k<<<gL, WG, 0, stream>>>(G0, slot, meta, nsrc, W2, b2, nullptr, out,
                                 n, 0, 0u, 0u);
}